// Round 5
// baseline (8901.395 us; speedup 1.0000x reference)
//
#include <hip/hip_runtime.h>
#include <cstdint>
#include <cstddef>

#define N_NODES 100000
#define N_EDGES 400000
#define IN_F 64
#define ED_F 16
#define C_F 128
#define L_LAYERS 3
#define G_GRAPHS 4096
#define OUT_F 128

// ---------------- generic fp32 tiled GEMM ----------------
// out[m,n] = act( sum_k A[m,k] * W[...] + bias[n] )
// WT: W is [Nn,K] row-major (apply W.T). Else W is [K,wld] row-major, use cols n0..n0+Nn.
// RELUA: relu on A load. ACT: 0 none, 1 relu, 2 sigmoid.
// A2S: virtual A = [A | relu(A2)], both [M,128], K must be 256.
#define BM 128
#define BN 64
#define BK 32
#define TM 8
#define TN 4

template<bool WT, bool RELUA, int ACT, bool BIAS, bool A2S>
__global__ __launch_bounds__(256) void gemm_kernel(
    const float* __restrict__ A, const float* __restrict__ A2,
    const float* __restrict__ W, const float* __restrict__ bias,
    float* __restrict__ out, int M, int K, int Nn, int wld)
{
  __shared__ float As[BK][BM + 4];   // +4 pad: conflict-free reads
  __shared__ float Ws[BK][BN];
  const int tid = threadIdx.x;
  const int tx = tid & 15;
  const int ty = tid >> 4;
  const int m0 = blockIdx.y * BM;
  const int n0 = blockIdx.x * BN;
  float acc[TM][TN];
#pragma unroll
  for (int i = 0; i < TM; i++)
#pragma unroll
    for (int j = 0; j < TN; j++) acc[i][j] = 0.f;

  for (int k0 = 0; k0 < K; k0 += BK) {
#pragma unroll
    for (int i = 0; i < 16; i++) {
      int idx = tid + i * 256;
      int k = idx & 31, m = idx >> 5;
      int gm = m0 + m, gk = k0 + k;
      float v = 0.f;
      if (gm < M && gk < K) {
        if (A2S) {
          v = (gk < C_F) ? A[(size_t)gm * C_F + gk]
                         : fmaxf(A2[(size_t)gm * C_F + (gk - C_F)], 0.f);
        } else {
          v = A[(size_t)gm * K + gk];
          if (RELUA) v = fmaxf(v, 0.f);
        }
      }
      As[k][m] = v;
    }
#pragma unroll
    for (int i = 0; i < 8; i++) {
      int idx = tid + i * 256;
      int n = idx & 63, k = idx >> 6;
      int gn = n0 + n, gk = k0 + k;
      float v = 0.f;
      if (gn < Nn && gk < K)
        v = WT ? W[(size_t)gn * K + gk] : W[(size_t)gk * wld + gn];
      Ws[k][n] = v;
    }
    __syncthreads();
#pragma unroll
    for (int kk = 0; kk < BK; kk++) {
      float a[TM], b[TN];
#pragma unroll
      for (int i = 0; i < TM; i++) a[i] = As[kk][ty * TM + i];
#pragma unroll
      for (int j = 0; j < TN; j++) b[j] = Ws[kk][tx * TN + j];
#pragma unroll
      for (int i = 0; i < TM; i++)
#pragma unroll
        for (int j = 0; j < TN; j++) acc[i][j] += a[i] * b[j];
    }
    __syncthreads();
  }
#pragma unroll
  for (int i = 0; i < TM; i++) {
    int gm = m0 + ty * TM + i;
    if (gm >= M) continue;
#pragma unroll
    for (int j = 0; j < TN; j++) {
      int gn = n0 + tx * TN + j;
      if (gn >= Nn) continue;
      float v = acc[i][j];
      if (BIAS) v += bias[gn];
      if (ACT == 1) v = fmaxf(v, 0.f);
      else if (ACT == 2) v = 1.f / (1.f + expf(-v));
      out[(size_t)gm * Nn + gn] = v;
    }
  }
}

// ---------------- zero fill (replaces hipMemsetAsync) ----------------
__global__ void zero_kernel(float* __restrict__ p, int n)
{
  int i = blockIdx.x * 256 + threadIdx.x;
  if (i < n) p[i] = 0.f;
}

// ---------------- per-layer weight packing ----------------
// bil2[c][s*128+d] = bil_w[l,s,c,d]    (128 x 256)
// gw[k][n]: k<128: gate_w[l,n,k]+gate_w[l,n,256+k]; k>=128: gate_w[l,n,k]-gate_w[l,n,k+128]
__global__ void pack_kernel(const float* __restrict__ bil_w,
                            const float* __restrict__ gate_w,
                            float* __restrict__ bil2, float* __restrict__ gw, int l)
{
  int i = blockIdx.x * 256 + threadIdx.x;
  if (i < 32768) {
    int c = i >> 8, sd = i & 255, s = sd >> 7, d = sd & 127;
    bil2[i] = bil_w[(((size_t)l * 2 + s) * 128 + c) * 128 + d];
  } else if (i < 65536) {
    int j = i - 32768;
    int k = j >> 7, n = j & 127;
    const float* g = gate_w + (size_t)l * 128 * 384 + (size_t)n * 384;
    gw[j] = (k < 128) ? (g[k] + g[256 + k]) : (g[k] - g[k + 128]);
  }
}

// ---------------- per-node pi/pj (1 wave per node) ----------------
__global__ __launch_bounds__(256) void p_kernel(const float* __restrict__ xn,
    const float* __restrict__ lin_w_l, float* __restrict__ p, int Nn)
{
  int node = (blockIdx.x * 256 + threadIdx.x) >> 6;
  int lane = threadIdx.x & 63;
  if (node >= Nn) return;
  const float* r = xn + (size_t)node * C_F;
  float v0 = r[lane], v1 = r[lane + 64];
  float pi0 = v0 * lin_w_l[lane]       + v1 * lin_w_l[64 + lane];
  float pi1 = v0 * lin_w_l[384 + lane] + v1 * lin_w_l[448 + lane];
  float pj0 = v0 * lin_w_l[256 + lane] + v1 * lin_w_l[320 + lane];
  float pj1 = v0 * lin_w_l[640 + lane] + v1 * lin_w_l[704 + lane];
#pragma unroll
  for (int off = 32; off > 0; off >>= 1) {
    pi0 += __shfl_xor(pi0, off); pi1 += __shfl_xor(pi1, off);
    pj0 += __shfl_xor(pj0, off); pj1 += __shfl_xor(pj1, off);
  }
  if (lane == 0) {
    p[(size_t)node * 4 + 0] = pi0; p[(size_t)node * 4 + 1] = pi1;
    p[(size_t)node * 4 + 2] = pj0; p[(size_t)node * 4 + 3] = pj1;
  }
}

// ---------------- fused per-edge pipeline (1 wave per edge) ----------------
// SMODE 2: z is [N,256], do both heads. SMODE 0/1: z is [N,128] for head s only.
template<int SMODE>
__global__ __launch_bounds__(256) void edge_kernel(
    const float* __restrict__ xn, const float* __restrict__ z,
    const float* __restrict__ en, const float* __restrict__ p,
    const float* __restrict__ lin_w_l, const float* __restrict__ lin_bias_l,
    const int* __restrict__ ei, float* __restrict__ hh, int e0, int ecount)
{
  int local = (blockIdx.x * 256 + threadIdx.x) >> 6;
  int lane = threadIdx.x & 63;
  if (local >= ecount) return;
  int eidx = e0 + local;
  int sidx = ei[eidx];             // src j
  int didx = ei[N_EDGES + eidx];   // dst i
  const float* xj = xn + (size_t)sidx * C_F;
  float xj0 = xj[lane], xj1 = xj[lane + 64];
  const float* enr = en + (size_t)local * C_F;
  float en0 = enr[lane], en1 = enr[lane + 64];
  if (SMODE == 2) {
    const float* zd = z + (size_t)didx * 256;
    float sc0 = zd[lane] * xj0 + zd[lane + 64] * xj1;
    float sc1 = zd[128 + lane] * xj0 + zd[192 + lane] * xj1;
    float ew0 = en0 * lin_w_l[128 + lane] + en1 * lin_w_l[192 + lane];
    float ew1 = en0 * lin_w_l[512 + lane] + en1 * lin_w_l[576 + lane];
#pragma unroll
    for (int off = 32; off > 0; off >>= 1) {
      sc0 += __shfl_xor(sc0, off);
      sc1 += __shfl_xor(sc1, off);
      ew0 += __shfl_xor(ew0, off);
      ew1 += __shfl_xor(ew1, off);
    }
    float a0 = tanhf(sc0 + ew0 + p[(size_t)didx * 4 + 0] + p[(size_t)sidx * 4 + 2] + lin_bias_l[0]);
    float a1 = tanhf(sc1 + ew1 + p[(size_t)didx * 4 + 1] + p[(size_t)sidx * 4 + 3] + lin_bias_l[1]);
    atomicAdd(&hh[(size_t)didx * C_F + lane],      fmaxf(xj0, en0) * a0);
    atomicAdd(&hh[(size_t)didx * C_F + lane + 64], fmaxf(xj1, en1) * a1);
  } else {
    const int s = SMODE;
    const float* zd = z + (size_t)didx * 128;
    float sc = zd[lane] * xj0 + zd[lane + 64] * xj1;
    float ew = (s == 0) ? (en0 * lin_w_l[128 + lane] + en1 * lin_w_l[192 + lane])
                        : (en0 * lin_w_l[512 + lane] + en1 * lin_w_l[576 + lane]);
#pragma unroll
    for (int off = 32; off > 0; off >>= 1) {
      sc += __shfl_xor(sc, off);
      ew += __shfl_xor(ew, off);
    }
    float a = tanhf(sc + ew + p[(size_t)didx * 4 + s] + p[(size_t)sidx * 4 + 2 + s] + lin_bias_l[s]);
    float m = (s == 0) ? fmaxf(xj0, en0) : fmaxf(xj1, en1);
    atomicAdd(&hh[(size_t)didx * C_F + s * 64 + lane], m * a);
  }
}

// ---------------- gated residual update ----------------
__global__ void update_kernel(float* __restrict__ h, const float* __restrict__ hh,
                              const float* __restrict__ beta, int total)
{
  int i = blockIdx.x * 256 + threadIdx.x;
  if (i >= total) return;
  float b = beta[i];
  h[i] = b * h[i] + (1.f - b) * fmaxf(hh[i], 0.f);
}

// ---------------- segment sum/max (batch sorted; h >= 0 so max 0-init ok) ----------------
template<bool DOMAX>
__global__ __launch_bounds__(256) void seg_kernel(const float* __restrict__ h,
    const int* __restrict__ batch, float* __restrict__ sm, float* __restrict__ mx, int Nn)
{
  int c = threadIdx.x & 127;
  int half = threadIdx.x >> 7;
  int nbase = blockIdx.x * 16 + half * 8;
  float asum = 0.f, amax = 0.f; int cur = -1;
  for (int i = 0; i < 8; i++) {
    int n = nbase + i;
    if (n >= Nn) break;
    int g = batch[n];
    float v = h[(size_t)n * C_F + c];
    if (g != cur) {
      if (cur >= 0) {
        atomicAdd(&sm[(size_t)cur * C_F + c], asum);
        if (DOMAX) atomicMax((int*)&mx[(size_t)cur * C_F + c], __float_as_int(amax));
      }
      cur = g; asum = 0.f; amax = 0.f;
    }
    asum += v;
    if (DOMAX) amax = fmaxf(amax, v);
  }
  if (cur >= 0) {
    atomicAdd(&sm[(size_t)cur * C_F + c], asum);
    if (DOMAX) atomicMax((int*)&mx[(size_t)cur * C_F + c], __float_as_int(amax));
  }
}

// ---------------- FeatureAttention MLP ----------------
__global__ __launch_bounds__(128) void featmlp(const float* __restrict__ mx,
    const float* __restrict__ sm, const float* __restrict__ w1,
    const float* __restrict__ w2, float* __restrict__ y)
{
  __shared__ float smx[128], ssm[128], t1[32], t2[32];
  int g = blockIdx.x; int t = threadIdx.x;
  smx[t] = mx[(size_t)g * 128 + t];
  ssm[t] = sm[(size_t)g * 128 + t];
  __syncthreads();
  if (t < 32) {
    float a1 = 0.f, a2 = 0.f;
    for (int c = 0; c < 128; c++) {
      float w = w1[t * 128 + c];
      a1 += smx[c] * w; a2 += ssm[c] * w;
    }
    t1[t] = fmaxf(a1, 0.f); t2[t] = fmaxf(a2, 0.f);
  }
  __syncthreads();
  float a = 0.f;
  for (int j = 0; j < 32; j++) a += (t1[j] + t2[j]) * w2[t * 32 + j];
  y[(size_t)g * 128 + t] = 1.f / (1.f + expf(-a));
}

// ---------------- h *= y[batch] ----------------
__global__ void scale_kernel(float* __restrict__ h, const float* __restrict__ y,
                             const int* __restrict__ batch, int total)
{
  int i = blockIdx.x * 256 + threadIdx.x;
  if (i >= total) return;
  h[i] *= y[(size_t)batch[i >> 7] * C_F + (i & 127)];
}

extern "C" void kernel_launch(void* const* d_in, const int* in_sizes, int n_in,
                              void* d_out, int out_size, void* d_ws, size_t ws_size,
                              hipStream_t stream)
{
  const float* x         = (const float*)d_in[0];
  const float* edge_attr = (const float*)d_in[1];
  const float* lin_a_w   = (const float*)d_in[2];
  const float* lin_a_b   = (const float*)d_in[3];
  const float* lin_b_w   = (const float*)d_in[4];
  const float* lin_b_b   = (const float*)d_in[5];
  const float* wn        = (const float*)d_in[6];
  const float* we        = (const float*)d_in[7];
  const float* bil_w     = (const float*)d_in[8];
  const float* lin_w     = (const float*)d_in[9];
  const float* lin_bias  = (const float*)d_in[10];
  const float* gate_w    = (const float*)d_in[11];
  const float* gate_b    = (const float*)d_in[12];
  const float* att_w1    = (const float*)d_in[13];
  const float* att_w2    = (const float*)d_in[14];
  const float* out_w     = (const float*)d_in[15];
  const float* out_b     = (const float*)d_in[16];
  const int*   ei        = (const int*)d_in[17];
  const int*   batch     = (const int*)d_in[18];
  (void)in_sizes; (void)n_in;

  float* ws = (float*)d_ws;
  const size_t availf = ws_size / sizeof(float);
  const size_t NH = (size_t)N_NODES * C_F;
  const size_t GH = (size_t)G_GRAPHS * C_F;

  size_t off = 0;
  float* h    = ws + off; off += NH;
  float* xn   = ws + off; off += NH;
  float* hh   = ws + off; off += NH;
  float* p    = ws + off; off += (size_t)N_NODES * 4;
  float* mx   = ws + off; off += GH;   // mx and smv contiguous (zeroed together)
  float* smv  = ws + off; off += GH;
  float* yv   = ws + off; off += GH;
  float* mol  = ws + off; off += GH;
  float* bil2 = ws + off; off += 32768;
  float* gw   = ws + off; off += 32768;
  const size_t fixedf = off;

  // ---- plan selection (depends only on ws_size: identical work every call) ----
  const size_t ZA = (size_t)N_NODES * 256;   // full z
  const size_t ZB = (size_t)N_NODES * 128;   // per-head z
  const int cand[5] = {100000, 50000, 25000, 12500, 6250};
  int plan = -1, chunk = 0;
  for (int i = 0; i < 5 && plan < 0; i++)
    if (fixedf + ZA + (size_t)2 * cand[i] * C_F <= availf) { plan = 0; chunk = cand[i]; }
  for (int i = 0; i < 5 && plan < 0; i++)
    if (fixedf + ZB + (size_t)2 * cand[i] * C_F <= availf) { plan = 1; chunk = cand[i]; }

  dim3 blk(256);
  if (plan < 0) {  // workspace too small: clean diagnostic failure instead of fault
    zero_kernel<<<dim3((out_size + 255) / 256), blk, 0, stream>>>((float*)d_out, out_size);
    return;
  }

  float* z    = ws + fixedf;
  float* ech  = z + (plan == 0 ? ZA : ZB);
  float* ench = ech + (size_t)chunk * C_F;
  float* beta = z;  // z dead by beta time

  const int total_h = N_NODES * C_F;

  // h = relu(x @ lin_a_w.T + lin_a_b)
  gemm_kernel<true, false, 1, true, false><<<dim3(C_F / BN, (N_NODES + BM - 1) / BM), blk, 0, stream>>>(
      x, nullptr, lin_a_w, lin_a_b, h, N_NODES, IN_F, C_F, C_F);

  for (int l = 0; l < L_LAYERS; l++) {
    pack_kernel<<<dim3(256), blk, 0, stream>>>(bil_w, gate_w, bil2, gw, l);
    // xn = h @ wn[l]
    gemm_kernel<false, false, 0, false, false><<<dim3(C_F / BN, (N_NODES + BM - 1) / BM), blk, 0, stream>>>(
        h, nullptr, wn + (size_t)l * C_F * C_F, nullptr, xn, N_NODES, C_F, C_F, C_F);
    // pi/pj per node
    p_kernel<<<dim3((N_NODES * 64 + 255) / 256), blk, 0, stream>>>(
        xn, lin_w + (size_t)l * 768, p, N_NODES);

    zero_kernel<<<dim3((total_h + 255) / 256), blk, 0, stream>>>(hh, total_h);

    if (plan == 0) {
      // z = xn @ bil2   [N, 256]
      gemm_kernel<false, false, 0, false, false><<<dim3(256 / BN, (N_NODES + BM - 1) / BM), blk, 0, stream>>>(
          xn, nullptr, bil2, nullptr, z, N_NODES, C_F, 256, 256);
      for (int c0 = 0; c0 < N_EDGES; c0 += chunk) {
        int cnt = (N_EDGES - c0 < chunk) ? (N_EDGES - c0) : chunk;
        gemm_kernel<true, false, 1, true, false><<<dim3(C_F / BN, (cnt + BM - 1) / BM), blk, 0, stream>>>(
            edge_attr + (size_t)c0 * ED_F, nullptr, lin_b_w, lin_b_b, ech, cnt, ED_F, C_F, C_F);
        gemm_kernel<false, false, 0, false, false><<<dim3(C_F / BN, (cnt + BM - 1) / BM), blk, 0, stream>>>(
            ech, nullptr, we + (size_t)l * C_F * C_F, nullptr, ench, cnt, C_F, C_F, C_F);
        edge_kernel<2><<<dim3((cnt * 64 + 255) / 256), blk, 0, stream>>>(
            xn, z, ench, p, lin_w + (size_t)l * 768, lin_bias + (size_t)l * 2, ei, hh, c0, cnt);
      }
    } else {
      for (int s = 0; s < 2; s++) {
        // z_s = xn @ bil2[:, s*128:(s+1)*128]   [N, 128]
        gemm_kernel<false, false, 0, false, false><<<dim3(C_F / BN, (N_NODES + BM - 1) / BM), blk, 0, stream>>>(
            xn, nullptr, bil2 + s * 128, nullptr, z, N_NODES, C_F, C_F, 256);
        for (int c0 = 0; c0 < N_EDGES; c0 += chunk) {
          int cnt = (N_EDGES - c0 < chunk) ? (N_EDGES - c0) : chunk;
          gemm_kernel<true, false, 1, true, false><<<dim3(C_F / BN, (cnt + BM - 1) / BM), blk, 0, stream>>>(
              edge_attr + (size_t)c0 * ED_F, nullptr, lin_b_w, lin_b_b, ech, cnt, ED_F, C_F, C_F);
          gemm_kernel<false, false, 0, false, false><<<dim3(C_F / BN, (cnt + BM - 1) / BM), blk, 0, stream>>>(
              ech, nullptr, we + (size_t)l * C_F * C_F, nullptr, ench, cnt, C_F, C_F, C_F);
          if (s == 0)
            edge_kernel<0><<<dim3((cnt * 64 + 255) / 256), blk, 0, stream>>>(
                xn, z, ench, p, lin_w + (size_t)l * 768, lin_bias + (size_t)l * 2, ei, hh, c0, cnt);
          else
            edge_kernel<1><<<dim3((cnt * 64 + 255) / 256), blk, 0, stream>>>(
                xn, z, ench, p, lin_w + (size_t)l * 768, lin_bias + (size_t)l * 2, ei, hh, c0, cnt);
        }
      }
    }

    // beta = sigmoid([h | relu(hh)] @ gw + gate_b[l])
    gemm_kernel<false, false, 2, true, true><<<dim3(C_F / BN, (N_NODES + BM - 1) / BM), blk, 0, stream>>>(
        h, hh, gw, gate_b + (size_t)l * C_F, beta, N_NODES, 256, C_F, C_F);
    update_kernel<<<dim3((total_h + 255) / 256), blk, 0, stream>>>(h, hh, beta, total_h);

    // FeatureAttention
    zero_kernel<<<dim3((int)(2 * GH + 255) / 256, 1), blk, 0, stream>>>(mx, (int)(2 * GH));
    seg_kernel<true><<<dim3((N_NODES + 15) / 16), blk, 0, stream>>>(h, batch, smv, mx, N_NODES);
    featmlp<<<dim3(G_GRAPHS), dim3(128), 0, stream>>>(
        mx, smv, att_w1 + (size_t)l * 32 * 128, att_w2 + (size_t)l * 128 * 32, yv);
    scale_kernel<<<dim3((total_h + 255) / 256), blk, 0, stream>>>(h, yv, batch, total_h);
  }

  // mol = relu(segment_sum(h)); out = mol @ out_w.T + out_b
  zero_kernel<<<dim3((int)(GH + 255) / 256, 1), blk, 0, stream>>>(mol, (int)GH);
  seg_kernel<false><<<dim3((N_NODES + 15) / 16), blk, 0, stream>>>(h, batch, mol, nullptr, N_NODES);
  gemm_kernel<true, true, 0, true, false><<<dim3(OUT_F / BN, (G_GRAPHS + BM - 1) / BM), blk, 0, stream>>>(
      mol, nullptr, out_w, out_b, (float*)d_out, G_GRAPHS, C_F, OUT_F, OUT_F);
}

// Round 8
// 5606.574 us; speedup vs baseline: 1.5877x; 1.5877x over previous
//
#include <hip/hip_runtime.h>
#include <cstdint>
#include <cstddef>

#define N_NODES 100000
#define N_EDGES 400000
#define IN_F 64
#define ED_F 16
#define C_F 128
#define L_LAYERS 3
#define G_GRAPHS 4096
#define OUT_F 128

// ---------------- generic fp32 tiled GEMM, BM=128 BN=128 ----------------
// WT: W is [Nn,K] row-major (apply W.T). Else W is [K,wld] row-major, cols n0...
// RELUA: relu on A load. ACT: 0 none, 1 relu, 2 sigmoid.
// A2S: virtual A = [A | relu(A2)], both [M,128], K must be 256.
#define BM 128
#define BN 128
#define BK 32
#define TM 8

template<bool WT, bool RELUA, int ACT, bool BIAS, bool A2S>
__global__ __launch_bounds__(256) void gemm_kernel(
    const float* __restrict__ A, const float* __restrict__ A2,
    const float* __restrict__ W, const float* __restrict__ bias,
    float* __restrict__ out, int M, int K, int Nn, int wld)
{
  __shared__ float As[BK][BM + 4];
  __shared__ float Ws[BK][BN];
  const int tid = threadIdx.x;
  const int tx = tid & 15;
  const int ty = tid >> 4;
  const int m0 = blockIdx.y * BM;
  const int n0 = blockIdx.x * BN;
  float acc[TM][8];
#pragma unroll
  for (int i = 0; i < TM; i++)
#pragma unroll
    for (int j = 0; j < 8; j++) acc[i][j] = 0.f;

  for (int k0 = 0; k0 < K; k0 += BK) {
#pragma unroll
    for (int i = 0; i < 16; i++) {
      int idx = tid + i * 256;
      int k = idx & 31, m = idx >> 5;
      int gm = m0 + m, gk = k0 + k;
      float v = 0.f;
      if (gm < M && gk < K) {
        if (A2S) {
          v = (gk < C_F) ? A[(size_t)gm * C_F + gk]
                         : fmaxf(A2[(size_t)gm * C_F + (gk - C_F)], 0.f);
        } else {
          v = A[(size_t)gm * K + gk];
          if (RELUA) v = fmaxf(v, 0.f);
        }
      }
      As[k][m] = v;
    }
#pragma unroll
    for (int i = 0; i < 16; i++) {
      int idx = tid + i * 256;
      int n = idx & 127, k = idx >> 7;
      int gn = n0 + n, gk = k0 + k;
      float v = 0.f;
      if (gn < Nn && gk < K)
        v = WT ? W[(size_t)gn * K + gk] : W[(size_t)gk * wld + gn];
      Ws[k][n] = v;
    }
    __syncthreads();
#pragma unroll
    for (int kk = 0; kk < BK; kk++) {
      float a[TM], b[8];
#pragma unroll
      for (int i = 0; i < TM; i++) a[i] = As[kk][ty * TM + i];
#pragma unroll
      for (int j = 0; j < 4; j++) {
        b[j]     = Ws[kk][tx * 4 + j];
        b[4 + j] = Ws[kk][64 + tx * 4 + j];
      }
#pragma unroll
      for (int i = 0; i < TM; i++)
#pragma unroll
        for (int j = 0; j < 8; j++) acc[i][j] += a[i] * b[j];
    }
    __syncthreads();
  }
#pragma unroll
  for (int i = 0; i < TM; i++) {
    int gm = m0 + ty * TM + i;
    if (gm >= M) continue;
#pragma unroll
    for (int j = 0; j < 8; j++) {
      int gn = n0 + ((j < 4) ? (tx * 4 + j) : (64 + tx * 4 + (j - 4)));
      if (gn >= Nn) continue;
      float v = acc[i][j];
      if (BIAS) v += bias[gn];
      if (ACT == 1) v = fmaxf(v, 0.f);
      else if (ACT == 2) v = 1.f / (1.f + expf(-v));
      out[(size_t)gm * Nn + gn] = v;
    }
  }
}

// ---------------- zero fill ----------------
__global__ void zero_kernel(float* __restrict__ p, int n)
{
  int i = blockIdx.x * 256 + threadIdx.x;
  if (i < n) p[i] = 0.f;
}

// ---------------- per-layer weight packing ----------------
// bil2[c][s*128+d] = bil_w[l,s,c,d]    (128 x 256)
// gw[k][n]: k<128: gate_w[l,n,k]+gate_w[l,n,256+k]; k>=128: gate_w[l,n,k]-gate_w[l,n,k+128]
__global__ void pack_kernel(const float* __restrict__ bil_w,
                            const float* __restrict__ gate_w,
                            float* __restrict__ bil2, float* __restrict__ gw, int l)
{
  int i = blockIdx.x * 256 + threadIdx.x;
  if (i < 32768) {
    int c = i >> 8, sd = i & 255, s = sd >> 7, d = sd & 127;
    bil2[i] = bil_w[(((size_t)l * 2 + s) * 128 + c) * 128 + d];
  } else if (i < 65536) {
    int j = i - 32768;
    int k = j >> 7, n = j & 127;
    const float* g = gate_w + (size_t)l * 128 * 384 + (size_t)n * 384;
    gw[j] = (k < 128) ? (g[k] + g[256 + k]) : (g[k] - g[k + 128]);
  }
}

// ---------------- per-node pi/pj (1 wave per node) ----------------
__global__ __launch_bounds__(256) void p_kernel(const float* __restrict__ xn,
    const float* __restrict__ lin_w_l, float* __restrict__ p, int Nn)
{
  int node = (blockIdx.x * 256 + threadIdx.x) >> 6;
  int lane = threadIdx.x & 63;
  if (node >= Nn) return;
  const float* r = xn + (size_t)node * C_F;
  float v0 = r[lane], v1 = r[lane + 64];
  float pi0 = v0 * lin_w_l[lane]       + v1 * lin_w_l[64 + lane];
  float pi1 = v0 * lin_w_l[384 + lane] + v1 * lin_w_l[448 + lane];
  float pj0 = v0 * lin_w_l[256 + lane] + v1 * lin_w_l[320 + lane];
  float pj1 = v0 * lin_w_l[640 + lane] + v1 * lin_w_l[704 + lane];
#pragma unroll
  for (int off = 32; off > 0; off >>= 1) {
    pi0 += __shfl_xor(pi0, off); pi1 += __shfl_xor(pi1, off);
    pj0 += __shfl_xor(pj0, off); pj1 += __shfl_xor(pj1, off);
  }
  if (lane == 0) {
    p[(size_t)node * 4 + 0] = pi0; p[(size_t)node * 4 + 1] = pi1;
    p[(size_t)node * 4 + 2] = pj0; p[(size_t)node * 4 + 3] = pj1;
  }
}

// ---------------- fused edge pipeline, all fp32 ----------------
// 256 thr = 4 waves; 64 edges/block (16/wave in 4 groups of 4).
// Lane owns channels (2*lane, 2*lane+1). In-kernel: e = relu(attr@lbw.T+lbb),
// en = e@we (we from L1/L2), score from fp32 z gather, tanh, atomic scatter.
#define EPB 64
__global__ __launch_bounds__(256) void edge_fused(
    const float* __restrict__ xn, const float* __restrict__ z,
    const float* __restrict__ edge_attr, const float* __restrict__ p,
    const float* __restrict__ lbw, const float* __restrict__ lbb,
    const float* __restrict__ weL, const float* __restrict__ lin_w_l,
    const float* __restrict__ lin_bias_l, const int* __restrict__ ei,
    float* __restrict__ hh)
{
  __shared__ float e_s[4][4][128];   // 4 waves x 4 edges x 128 ch = 8 KB
  const int tid = threadIdx.x;
  const int wave = tid >> 6, lane = tid & 63;
  const int c0 = lane * 2;

  // hoist per-channel weights (fp32)
  const float4* r0 = (const float4*)(lbw + (size_t)c0 * ED_F);
  const float4* r1 = (const float4*)(lbw + (size_t)(c0 + 1) * ED_F);
  float4 w0a = r0[0], w0b = r0[1], w0c = r0[2], w0d = r0[3];
  float4 w1a = r1[0], w1b = r1[1], w1c = r1[2], w1d = r1[3];
  float bb0 = lbb[c0], bb1 = lbb[c0 + 1];
  float lw0a = lin_w_l[128 + c0], lw0b = lin_w_l[129 + c0];
  float lw1a = lin_w_l[512 + c0], lw1b = lin_w_l[513 + c0];
  float lbias0 = lin_bias_l[0], lbias1 = lin_bias_l[1];

  const int ebase = blockIdx.x * EPB + wave * 16;

  for (int g = 0; g < 4; g++) {
    const int e0 = ebase + g * 4;
    // ---- e for 4 edges, channels c0,c0+1 -> LDS ----
#pragma unroll
    for (int j = 0; j < 4; j++) {
      const float4* ar = (const float4*)(edge_attr + (size_t)(e0 + j) * ED_F);
      float4 a0 = ar[0], a1 = ar[1], a2 = ar[2], a3 = ar[3];
      float acc0 = bb0, acc1 = bb1;
      acc0 += a0.x*w0a.x + a0.y*w0a.y + a0.z*w0a.z + a0.w*w0a.w;
      acc0 += a1.x*w0b.x + a1.y*w0b.y + a1.z*w0b.z + a1.w*w0b.w;
      acc0 += a2.x*w0c.x + a2.y*w0c.y + a2.z*w0c.z + a2.w*w0c.w;
      acc0 += a3.x*w0d.x + a3.y*w0d.y + a3.z*w0d.z + a3.w*w0d.w;
      acc1 += a0.x*w1a.x + a0.y*w1a.y + a0.z*w1a.z + a0.w*w1a.w;
      acc1 += a1.x*w1b.x + a1.y*w1b.y + a1.z*w1b.z + a1.w*w1b.w;
      acc1 += a2.x*w1c.x + a2.y*w1c.y + a2.z*w1c.z + a2.w*w1c.w;
      acc1 += a3.x*w1d.x + a3.y*w1d.y + a3.z*w1d.z + a3.w*w1d.w;
      float2 ev = make_float2(fmaxf(acc0, 0.f), fmaxf(acc1, 0.f));
      ((float2*)e_s[wave][j])[lane] = ev;
    }
    __builtin_amdgcn_wave_barrier();   // order LDS writes before cross-lane reads

    // ---- en = e @ we : channels c0,c0+1 for 4 edges ----
    float ena[4] = {0.f, 0.f, 0.f, 0.f}, enb[4] = {0.f, 0.f, 0.f, 0.f};
#pragma unroll 8
    for (int k = 0; k < 128; k++) {
      float2 wv = *(const float2*)(weL + (size_t)k * C_F + c0);
#pragma unroll
      for (int j = 0; j < 4; j++) {
        float ev = e_s[wave][j][k];
        ena[j] += ev * wv.x;
        enb[j] += ev * wv.y;
      }
    }
    __builtin_amdgcn_wave_barrier();   // reads done before next group's writes

    // ---- score + block + tanh + scatter ----
#pragma unroll
    for (int j = 0; j < 4; j++) {
      int e = e0 + j;
      int sidx = ei[e];              // src
      int didx = ei[N_EDGES + e];    // dst
      float2 xj = *(const float2*)(xn + (size_t)sidx * C_F + c0);
      float2 z0 = *(const float2*)(z + (size_t)didx * 256 + c0);
      float2 z1 = *(const float2*)(z + (size_t)didx * 256 + 128 + c0);
      float rr0 = z0.x * xj.x + z0.y * xj.y + ena[j] * lw0a + enb[j] * lw0b;
      float rr1 = z1.x * xj.x + z1.y * xj.y + ena[j] * lw1a + enb[j] * lw1b;
#pragma unroll
      for (int off = 32; off > 0; off >>= 1) {
        rr0 += __shfl_xor(rr0, off);
        rr1 += __shfl_xor(rr1, off);
      }
      float al0 = tanhf(rr0 + p[(size_t)didx * 4 + 0] + p[(size_t)sidx * 4 + 2] + lbias0);
      float al1 = tanhf(rr1 + p[(size_t)didx * 4 + 1] + p[(size_t)sidx * 4 + 3] + lbias1);
      float aj = (lane < 32) ? al0 : al1;   // s = channel>>6; c0,c0+1 share s
      atomicAdd(&hh[(size_t)didx * C_F + c0],     fmaxf(xj.x, ena[j]) * aj);
      atomicAdd(&hh[(size_t)didx * C_F + c0 + 1], fmaxf(xj.y, enb[j]) * aj);
    }
  }
}

// ---------------- gated residual update ----------------
__global__ void update_kernel(float* __restrict__ h, const float* __restrict__ hh,
                              const float* __restrict__ beta, int total)
{
  int i = blockIdx.x * 256 + threadIdx.x;
  if (i >= total) return;
  float b = beta[i];
  h[i] = b * h[i] + (1.f - b) * fmaxf(hh[i], 0.f);
}

// ---------------- segment sum/max (batch sorted; h >= 0 so max 0-init ok) ----------------
template<bool DOMAX>
__global__ __launch_bounds__(256) void seg_kernel(const float* __restrict__ h,
    const int* __restrict__ batch, float* __restrict__ sm, float* __restrict__ mx, int Nn)
{
  int c = threadIdx.x & 127;
  int half = threadIdx.x >> 7;
  int nbase = blockIdx.x * 16 + half * 8;
  float asum = 0.f, amax = 0.f; int cur = -1;
  for (int i = 0; i < 8; i++) {
    int n = nbase + i;
    if (n >= Nn) break;
    int g = batch[n];
    float v = h[(size_t)n * C_F + c];
    if (g != cur) {
      if (cur >= 0) {
        atomicAdd(&sm[(size_t)cur * C_F + c], asum);
        if (DOMAX) atomicMax((int*)&mx[(size_t)cur * C_F + c], __float_as_int(amax));
      }
      cur = g; asum = 0.f; amax = 0.f;
    }
    asum += v;
    if (DOMAX) amax = fmaxf(amax, v);
  }
  if (cur >= 0) {
    atomicAdd(&sm[(size_t)cur * C_F + c], asum);
    if (DOMAX) atomicMax((int*)&mx[(size_t)cur * C_F + c], __float_as_int(amax));
  }
}

// ---------------- FeatureAttention MLP ----------------
__global__ __launch_bounds__(128) void featmlp(const float* __restrict__ mx,
    const float* __restrict__ sm, const float* __restrict__ w1,
    const float* __restrict__ w2, float* __restrict__ y)
{
  __shared__ float smx[128], ssm[128], t1[32], t2[32];
  int g = blockIdx.x; int t = threadIdx.x;
  smx[t] = mx[(size_t)g * 128 + t];
  ssm[t] = sm[(size_t)g * 128 + t];
  __syncthreads();
  if (t < 32) {
    float a1 = 0.f, a2 = 0.f;
    for (int c = 0; c < 128; c++) {
      float w = w1[t * 128 + c];
      a1 += smx[c] * w; a2 += ssm[c] * w;
    }
    t1[t] = fmaxf(a1, 0.f); t2[t] = fmaxf(a2, 0.f);
  }
  __syncthreads();
  float a = 0.f;
  for (int j = 0; j < 32; j++) a += (t1[j] + t2[j]) * w2[t * 32 + j];
  y[(size_t)g * 128 + t] = 1.f / (1.f + expf(-a));
}

// ---------------- h *= y[batch] ----------------
__global__ void scale_kernel(float* __restrict__ h, const float* __restrict__ y,
                             const int* __restrict__ batch, int total)
{
  int i = blockIdx.x * 256 + threadIdx.x;
  if (i >= total) return;
  h[i] *= y[(size_t)batch[i >> 7] * C_F + (i & 127)];
}

extern "C" void kernel_launch(void* const* d_in, const int* in_sizes, int n_in,
                              void* d_out, int out_size, void* d_ws, size_t ws_size,
                              hipStream_t stream)
{
  const float* x         = (const float*)d_in[0];
  const float* edge_attr = (const float*)d_in[1];
  const float* lin_a_w   = (const float*)d_in[2];
  const float* lin_a_b   = (const float*)d_in[3];
  const float* lin_b_w   = (const float*)d_in[4];
  const float* lin_b_b   = (const float*)d_in[5];
  const float* wn        = (const float*)d_in[6];
  const float* we        = (const float*)d_in[7];
  const float* bil_w     = (const float*)d_in[8];
  const float* lin_w     = (const float*)d_in[9];
  const float* lin_bias  = (const float*)d_in[10];
  const float* gate_w    = (const float*)d_in[11];
  const float* gate_b    = (const float*)d_in[12];
  const float* att_w1    = (const float*)d_in[13];
  const float* att_w2    = (const float*)d_in[14];
  const float* out_w     = (const float*)d_in[15];
  const float* out_b     = (const float*)d_in[16];
  const int*   ei        = (const int*)d_in[17];
  const int*   batch     = (const int*)d_in[18];
  (void)in_sizes; (void)n_in;

  float* ws = (float*)d_ws;
  const size_t availf = ws_size / sizeof(float);
  const size_t NH = (size_t)N_NODES * C_F;
  const size_t GH = (size_t)G_GRAPHS * C_F;

  size_t off = 0;
  float* h    = ws + off; off += NH;
  float* xn   = ws + off; off += NH;
  float* hh   = ws + off; off += NH;
  float* p    = ws + off; off += (size_t)N_NODES * 4;
  float* mx   = ws + off; off += GH;   // mx,smv contiguous (zeroed together)
  float* smv  = ws + off; off += GH;
  float* yv   = ws + off; off += GH;
  float* mol  = ws + off; off += GH;
  float* bil2 = ws + off; off += 32768;
  float* gw   = ws + off; off += 32768;
  float* z    = ws + off; off += (size_t)N_NODES * 256;   // fp32 [N,256]
  float* beta = z;   // z dead after edge_fused; beta needs N*128 <= N*256

  dim3 blk(256);
  if (off > availf) {  // 66.56M floats; known budget >= 79.36M -> never triggers
    zero_kernel<<<dim3((out_size + 255) / 256), blk, 0, stream>>>((float*)d_out, out_size);
    return;
  }

  const int total_h = N_NODES * C_F;

  // h = relu(x @ lin_a_w.T + lin_a_b)
  gemm_kernel<true, false, 1, true, false><<<dim3(1, (N_NODES + BM - 1) / BM), blk, 0, stream>>>(
      x, nullptr, lin_a_w, lin_a_b, h, N_NODES, IN_F, C_F, C_F);

  for (int l = 0; l < L_LAYERS; l++) {
    pack_kernel<<<dim3(256), blk, 0, stream>>>(bil_w, gate_w, bil2, gw, l);
    // xn = h @ wn[l]
    gemm_kernel<false, false, 0, false, false><<<dim3(1, (N_NODES + BM - 1) / BM), blk, 0, stream>>>(
        h, nullptr, wn + (size_t)l * C_F * C_F, nullptr, xn, N_NODES, C_F, C_F, C_F);
    // z = xn @ bil2   fp32 [N,256]
    gemm_kernel<false, false, 0, false, false><<<dim3(2, (N_NODES + BM - 1) / BM), blk, 0, stream>>>(
        xn, nullptr, bil2, nullptr, z, N_NODES, C_F, 256, 256);
    // pi/pj per node
    p_kernel<<<dim3((N_NODES * 64 + 255) / 256), blk, 0, stream>>>(
        xn, lin_w + (size_t)l * 768, p, N_NODES);

    zero_kernel<<<dim3((total_h + 255) / 256), blk, 0, stream>>>(hh, total_h);
    // fused: e = relu(attr@lbw.T+lbb), en = e@we[l], score, tanh, scatter
    edge_fused<<<dim3(N_EDGES / EPB), blk, 0, stream>>>(
        xn, z, edge_attr, p, lin_b_w, lin_b_b, we + (size_t)l * C_F * C_F,
        lin_w + (size_t)l * 768, lin_bias + (size_t)l * 2, ei, hh);

    // beta = sigmoid([h | relu(hh)] @ gw + gate_b[l])
    gemm_kernel<false, false, 2, true, true><<<dim3(1, (N_NODES + BM - 1) / BM), blk, 0, stream>>>(
        h, hh, gw, gate_b + (size_t)l * C_F, beta, N_NODES, 256, C_F, C_F);
    update_kernel<<<dim3((total_h + 255) / 256), blk, 0, stream>>>(h, hh, beta, total_h);

    // FeatureAttention
    zero_kernel<<<dim3((int)(2 * GH + 255) / 256), blk, 0, stream>>>(mx, (int)(2 * GH));
    seg_kernel<true><<<dim3((N_NODES + 15) / 16), blk, 0, stream>>>(h, batch, smv, mx, N_NODES);
    featmlp<<<dim3(G_GRAPHS), dim3(128), 0, stream>>>(
        mx, smv, att_w1 + (size_t)l * 32 * 128, att_w2 + (size_t)l * 128 * 32, yv);
    scale_kernel<<<dim3((total_h + 255) / 256), blk, 0, stream>>>(h, yv, batch, total_h);
  }

  // mol = relu(segment_sum(h)); out = mol @ out_w.T + out_b
  zero_kernel<<<dim3((int)(GH + 255) / 256), blk, 0, stream>>>(mol, (int)GH);
  seg_kernel<false><<<dim3((N_NODES + 15) / 16), blk, 0, stream>>>(h, batch, mol, nullptr, N_NODES);
  gemm_kernel<true, true, 0, true, false><<<dim3(1, (G_GRAPHS + BM - 1) / BM), blk, 0, stream>>>(
      mol, nullptr, out_w, out_b, (float*)d_out, G_GRAPHS, C_F, OUT_F, OUT_F);
}

// Round 11
// 5562.273 us; speedup vs baseline: 1.6003x; 1.0080x over previous
//
#include <hip/hip_runtime.h>
#include <cstdint>
#include <cstddef>

#define N_NODES 100000
#define N_EDGES 400000
#define IN_F 64
#define ED_F 16
#define C_F 128
#define L_LAYERS 3
#define G_GRAPHS 4096
#define OUT_F 128

// ---------------- generic fp32 tiled GEMM, BM=128 BN=128 ----------------
// WT: W is [Nn,K] row-major (apply W.T). Else W is [K,wld] row-major.
// RELUA: relu on A load. ACT: 0 none, 1 relu, 2 sigmoid.
// A2S: virtual A = [A | relu(A2)], both [M,128], K must be 256.
// OMODE: 0 normal (out, leading dim old); 1 split: col<128 -> out[gm*128+col],
//        col>=128 -> out2[gm*256+(col-128)]  (Nn must be 384).
#define BM 128
#define BN 128
#define BK 32
#define TM 8

template<bool WT, bool RELUA, int ACT, bool BIAS, bool A2S, int OMODE>
__global__ __launch_bounds__(256) void gemm_kernel(
    const float* __restrict__ A, const float* __restrict__ A2,
    const float* __restrict__ W, const float* __restrict__ bias,
    float* __restrict__ out, float* __restrict__ out2,
    int M, int K, int Nn, int wld, int old)
{
  __shared__ float As[BK][BM + 4];
  __shared__ float Ws[BK][BN];
  const int tid = threadIdx.x;
  const int tx = tid & 15;
  const int ty = tid >> 4;
  const int m0 = blockIdx.y * BM;
  const int n0 = blockIdx.x * BN;
  float acc[TM][8];
#pragma unroll
  for (int i = 0; i < TM; i++)
#pragma unroll
    for (int j = 0; j < 8; j++) acc[i][j] = 0.f;

  for (int k0 = 0; k0 < K; k0 += BK) {
#pragma unroll
    for (int i = 0; i < 16; i++) {
      int idx = tid + i * 256;
      int k = idx & 31, m = idx >> 5;
      int gm = m0 + m, gk = k0 + k;
      float v = 0.f;
      if (gm < M && gk < K) {
        if (A2S) {
          v = (gk < C_F) ? A[(size_t)gm * C_F + gk]
                         : fmaxf(A2[(size_t)gm * C_F + (gk - C_F)], 0.f);
        } else {
          v = A[(size_t)gm * K + gk];
          if (RELUA) v = fmaxf(v, 0.f);
        }
      }
      As[k][m] = v;
    }
#pragma unroll
    for (int i = 0; i < 16; i++) {
      int idx = tid + i * 256;
      int n = idx & 127, k = idx >> 7;
      int gn = n0 + n, gk = k0 + k;
      float v = 0.f;
      if (gn < Nn && gk < K)
        v = WT ? W[(size_t)gn * K + gk] : W[(size_t)gk * wld + gn];
      Ws[k][n] = v;
    }
    __syncthreads();
#pragma unroll
    for (int kk = 0; kk < BK; kk++) {
      float a[TM], b[8];
#pragma unroll
      for (int i = 0; i < TM; i++) a[i] = As[kk][ty * TM + i];
#pragma unroll
      for (int j = 0; j < 4; j++) {
        b[j]     = Ws[kk][tx * 4 + j];
        b[4 + j] = Ws[kk][64 + tx * 4 + j];
      }
#pragma unroll
      for (int i = 0; i < TM; i++)
#pragma unroll
        for (int j = 0; j < 8; j++) acc[i][j] += a[i] * b[j];
    }
    __syncthreads();
  }
#pragma unroll
  for (int i = 0; i < TM; i++) {
    int gm = m0 + ty * TM + i;
    if (gm >= M) continue;
#pragma unroll
    for (int j = 0; j < 8; j++) {
      int gn = n0 + ((j < 4) ? (tx * 4 + j) : (64 + tx * 4 + (j - 4)));
      if (gn >= Nn) continue;
      float v = acc[i][j];
      if (BIAS) v += bias[gn];
      if (ACT == 1) v = fmaxf(v, 0.f);
      else if (ACT == 2) v = 1.f / (1.f + expf(-v));
      if (OMODE == 0) {
        out[(size_t)gm * old + gn] = v;
      } else {  // split [xn | z]
        if (gn < C_F) out[(size_t)gm * C_F + gn] = v;
        else          out2[(size_t)gm * 256 + (gn - C_F)] = v;
      }
    }
  }
}

// ---------------- zero fill ----------------
__global__ void zero_kernel(float* __restrict__ p, int n)
{
  int i = blockIdx.x * 256 + threadIdx.x;
  if (i < n) p[i] = 0.f;
}

// ---------------- per-layer weight packing ----------------
// bil2[c][s*128+d] = bil_w[l,s,c,d]; gw fold; Wz[:,0:128] = wn[l]
__global__ void pack_kernel(const float* __restrict__ bil_w,
                            const float* __restrict__ gate_w,
                            const float* __restrict__ wn,
                            float* __restrict__ bil2, float* __restrict__ gw,
                            float* __restrict__ Wz, int l)
{
  int i = blockIdx.x * 256 + threadIdx.x;
  if (i < 32768) {
    int c = i >> 8, sd = i & 255, s = sd >> 7, d = sd & 127;
    bil2[i] = bil_w[(((size_t)l * 2 + s) * 128 + c) * 128 + d];
  } else if (i < 65536) {
    int j = i - 32768;
    int k = j >> 7, n = j & 127;
    const float* g = gate_w + (size_t)l * 128 * 384 + (size_t)n * 384;
    gw[j] = (k < 128) ? (g[k] + g[256 + k]) : (g[k] - g[k + 128]);
  } else if (i < 81920) {
    int j = i - 65536;
    int k = j >> 7, n = j & 127;
    Wz[(size_t)k * 384 + n] = wn[(size_t)l * 16384 + j];
  }
}

// ---------------- per-node pi/pj (1 wave per node) ----------------
__global__ __launch_bounds__(256) void p_kernel(const float* __restrict__ xn,
    const float* __restrict__ lin_w_l, float* __restrict__ p, int Nn)
{
  int node = (blockIdx.x * 256 + threadIdx.x) >> 6;
  int lane = threadIdx.x & 63;
  if (node >= Nn) return;
  const float* r = xn + (size_t)node * C_F;
  float v0 = r[lane], v1 = r[lane + 64];
  float pi0 = v0 * lin_w_l[lane]       + v1 * lin_w_l[64 + lane];
  float pi1 = v0 * lin_w_l[384 + lane] + v1 * lin_w_l[448 + lane];
  float pj0 = v0 * lin_w_l[256 + lane] + v1 * lin_w_l[320 + lane];
  float pj1 = v0 * lin_w_l[640 + lane] + v1 * lin_w_l[704 + lane];
#pragma unroll
  for (int off = 32; off > 0; off >>= 1) {
    pi0 += __shfl_xor(pi0, off); pi1 += __shfl_xor(pi1, off);
    pj0 += __shfl_xor(pj0, off); pj1 += __shfl_xor(pj1, off);
  }
  if (lane == 0) {
    p[(size_t)node * 4 + 0] = pi0; p[(size_t)node * 4 + 1] = pi1;
    p[(size_t)node * 4 + 2] = pj0; p[(size_t)node * 4 + 3] = pj1;
  }
}

// ---------------- fused edge pipeline, all fp32 (R8-verbatim) ----------------
#define EPB 64
__global__ __launch_bounds__(256) void edge_fused(
    const float* __restrict__ xn, const float* __restrict__ z,
    const float* __restrict__ edge_attr, const float* __restrict__ p,
    const float* __restrict__ lbw, const float* __restrict__ lbb,
    const float* __restrict__ weL, const float* __restrict__ lin_w_l,
    const float* __restrict__ lin_bias_l, const int* __restrict__ ei,
    float* __restrict__ hh)
{
  __shared__ float e_s[4][4][128];
  const int tid = threadIdx.x;
  const int wave = tid >> 6, lane = tid & 63;
  const int c0 = lane * 2;

  const float4* r0 = (const float4*)(lbw + (size_t)c0 * ED_F);
  const float4* r1 = (const float4*)(lbw + (size_t)(c0 + 1) * ED_F);
  float4 w0a = r0[0], w0b = r0[1], w0c = r0[2], w0d = r0[3];
  float4 w1a = r1[0], w1b = r1[1], w1c = r1[2], w1d = r1[3];
  float bb0 = lbb[c0], bb1 = lbb[c0 + 1];
  float lw0a = lin_w_l[128 + c0], lw0b = lin_w_l[129 + c0];
  float lw1a = lin_w_l[512 + c0], lw1b = lin_w_l[513 + c0];
  float lbias0 = lin_bias_l[0], lbias1 = lin_bias_l[1];

  const int ebase = blockIdx.x * EPB + wave * 16;

  for (int g = 0; g < 4; g++) {
    const int e0 = ebase + g * 4;
#pragma unroll
    for (int j = 0; j < 4; j++) {
      const float4* ar = (const float4*)(edge_attr + (size_t)(e0 + j) * ED_F);
      float4 a0 = ar[0], a1 = ar[1], a2 = ar[2], a3 = ar[3];
      float acc0 = bb0, acc1 = bb1;
      acc0 += a0.x*w0a.x + a0.y*w0a.y + a0.z*w0a.z + a0.w*w0a.w;
      acc0 += a1.x*w0b.x + a1.y*w0b.y + a1.z*w0b.z + a1.w*w0b.w;
      acc0 += a2.x*w0c.x + a2.y*w0c.y + a2.z*w0c.z + a2.w*w0c.w;
      acc0 += a3.x*w0d.x + a3.y*w0d.y + a3.z*w0d.z + a3.w*w0d.w;
      acc1 += a0.x*w1a.x + a0.y*w1a.y + a0.z*w1a.z + a0.w*w1a.w;
      acc1 += a1.x*w1b.x + a1.y*w1b.y + a1.z*w1b.z + a1.w*w1b.w;
      acc1 += a2.x*w1c.x + a2.y*w1c.y + a2.z*w1c.z + a2.w*w1c.w;
      acc1 += a3.x*w1d.x + a3.y*w1d.y + a3.z*w1d.z + a3.w*w1d.w;
      float2 ev = make_float2(fmaxf(acc0, 0.f), fmaxf(acc1, 0.f));
      ((float2*)e_s[wave][j])[lane] = ev;
    }
    __builtin_amdgcn_wave_barrier();

    float ena[4] = {0.f, 0.f, 0.f, 0.f}, enb[4] = {0.f, 0.f, 0.f, 0.f};
#pragma unroll 8
    for (int k = 0; k < 128; k++) {
      float2 wv = *(const float2*)(weL + (size_t)k * C_F + c0);
#pragma unroll
      for (int j = 0; j < 4; j++) {
        float ev = e_s[wave][j][k];
        ena[j] += ev * wv.x;
        enb[j] += ev * wv.y;
      }
    }
    __builtin_amdgcn_wave_barrier();

#pragma unroll
    for (int j = 0; j < 4; j++) {
      int e = e0 + j;
      int sidx = ei[e];
      int didx = ei[N_EDGES + e];
      float2 xj = *(const float2*)(xn + (size_t)sidx * C_F + c0);
      float2 z0 = *(const float2*)(z + (size_t)didx * 256 + c0);
      float2 z1 = *(const float2*)(z + (size_t)didx * 256 + 128 + c0);
      float rr0 = z0.x * xj.x + z0.y * xj.y + ena[j] * lw0a + enb[j] * lw0b;
      float rr1 = z1.x * xj.x + z1.y * xj.y + ena[j] * lw1a + enb[j] * lw1b;
#pragma unroll
      for (int off = 32; off > 0; off >>= 1) {
        rr0 += __shfl_xor(rr0, off);
        rr1 += __shfl_xor(rr1, off);
      }
      float al0 = tanhf(rr0 + p[(size_t)didx * 4 + 0] + p[(size_t)sidx * 4 + 2] + lbias0);
      float al1 = tanhf(rr1 + p[(size_t)didx * 4 + 1] + p[(size_t)sidx * 4 + 3] + lbias1);
      float aj = (lane < 32) ? al0 : al1;
      atomicAdd(&hh[(size_t)didx * C_F + c0],     fmaxf(xj.x, ena[j]) * aj);
      atomicAdd(&hh[(size_t)didx * C_F + c0 + 1], fmaxf(xj.y, enb[j]) * aj);
    }
  }
}

// ---------------- gated residual update ----------------
__global__ void update_kernel(float* __restrict__ h, const float* __restrict__ hh,
                              const float* __restrict__ beta, int total)
{
  int i = blockIdx.x * 256 + threadIdx.x;
  if (i >= total) return;
  float b = beta[i];
  h[i] = b * h[i] + (1.f - b) * fmaxf(hh[i], 0.f);
}

// ---------------- segment sum/max (batch sorted; h >= 0 so max 0-init ok) ----------------
template<bool DOMAX>
__global__ __launch_bounds__(256) void seg_kernel(const float* __restrict__ h,
    const int* __restrict__ batch, float* __restrict__ sm, float* __restrict__ mx, int Nn)
{
  int c = threadIdx.x & 127;
  int half = threadIdx.x >> 7;
  int nbase = blockIdx.x * 16 + half * 8;
  float asum = 0.f, amax = 0.f; int cur = -1;
  for (int i = 0; i < 8; i++) {
    int n = nbase + i;
    if (n >= Nn) break;
    int g = batch[n];
    float v = h[(size_t)n * C_F + c];
    if (g != cur) {
      if (cur >= 0) {
        atomicAdd(&sm[(size_t)cur * C_F + c], asum);
        if (DOMAX) atomicMax((int*)&mx[(size_t)cur * C_F + c], __float_as_int(amax));
      }
      cur = g; asum = 0.f; amax = 0.f;
    }
    asum += v;
    if (DOMAX) amax = fmaxf(amax, v);
  }
  if (cur >= 0) {
    atomicAdd(&sm[(size_t)cur * C_F + c], asum);
    if (DOMAX) atomicMax((int*)&mx[(size_t)cur * C_F + c], __float_as_int(amax));
  }
}

// ---------------- FeatureAttention MLP ----------------
__global__ __launch_bounds__(128) void featmlp(const float* __restrict__ mx,
    const float* __restrict__ sm, const float* __restrict__ w1,
    const float* __restrict__ w2, float* __restrict__ y)
{
  __shared__ float smx[128], ssm[128], t1[32], t2[32];
  int g = blockIdx.x; int t = threadIdx.x;
  smx[t] = mx[(size_t)g * 128 + t];
  ssm[t] = sm[(size_t)g * 128 + t];
  __syncthreads();
  if (t < 32) {
    float a1 = 0.f, a2 = 0.f;
    for (int c = 0; c < 128; c++) {
      float w = w1[t * 128 + c];
      a1 += smx[c] * w; a2 += ssm[c] * w;
    }
    t1[t] = fmaxf(a1, 0.f); t2[t] = fmaxf(a2, 0.f);
  }
  __syncthreads();
  float a = 0.f;
  for (int j = 0; j < 32; j++) a += (t1[j] + t2[j]) * w2[t * 32 + j];
  y[(size_t)g * 128 + t] = 1.f / (1.f + expf(-a));
}

// ---------------- h *= y[batch] ----------------
__global__ void scale_kernel(float* __restrict__ h, const float* __restrict__ y,
                             const int* __restrict__ batch, int total)
{
  int i = blockIdx.x * 256 + threadIdx.x;
  if (i >= total) return;
  h[i] *= y[(size_t)batch[i >> 7] * C_F + (i & 127)];
}

extern "C" void kernel_launch(void* const* d_in, const int* in_sizes, int n_in,
                              void* d_out, int out_size, void* d_ws, size_t ws_size,
                              hipStream_t stream)
{
  const float* x         = (const float*)d_in[0];
  const float* edge_attr = (const float*)d_in[1];
  const float* lin_a_w   = (const float*)d_in[2];
  const float* lin_a_b   = (const float*)d_in[3];
  const float* lin_b_w   = (const float*)d_in[4];
  const float* lin_b_b   = (const float*)d_in[5];
  const float* wn        = (const float*)d_in[6];
  const float* we        = (const float*)d_in[7];
  const float* bil_w     = (const float*)d_in[8];
  const float* lin_w     = (const float*)d_in[9];
  const float* lin_bias  = (const float*)d_in[10];
  const float* gate_w    = (const float*)d_in[11];
  const float* gate_b    = (const float*)d_in[12];
  const float* att_w1    = (const float*)d_in[13];
  const float* att_w2    = (const float*)d_in[14];
  const float* out_w     = (const float*)d_in[15];
  const float* out_b     = (const float*)d_in[16];
  const int*   ei        = (const int*)d_in[17];
  const int*   batch     = (const int*)d_in[18];
  (void)in_sizes; (void)n_in;

  float* ws = (float*)d_ws;
  const size_t availf = ws_size / sizeof(float);
  const size_t NH = (size_t)N_NODES * C_F;
  const size_t GH = (size_t)G_GRAPHS * C_F;

  size_t off = 0;
  float* h    = ws + off; off += NH;
  float* xn   = ws + off; off += NH;
  float* hh   = ws + off; off += NH;
  float* p    = ws + off; off += (size_t)N_NODES * 4;
  float* mx   = ws + off; off += GH;   // mx,smv contiguous (zeroed together)
  float* smv  = ws + off; off += GH;
  float* yv   = ws + off; off += GH;
  float* mol  = ws + off; off += GH;
  float* bil2 = ws + off; off += 32768;
  float* gw   = ws + off; off += 32768;
  float* Wz   = ws + off; off += 49152;                   // [wn | wn@bil2] 128x384
  float* z    = ws + off; off += (size_t)N_NODES * 256;   // fp32 [N,256]
  float* beta = z;   // z dead after edge_fused

  dim3 blk(256);
  if (off > availf) {  // ~66.6M floats; known budget >= 79.36M
    zero_kernel<<<dim3((out_size + 255) / 256), blk, 0, stream>>>((float*)d_out, out_size);
    return;
  }

  const int total_h = N_NODES * C_F;

  // h = relu(x @ lin_a_w.T + lin_a_b)
  gemm_kernel<true, false, 1, true, false, 0><<<dim3(1, (N_NODES + BM - 1) / BM), blk, 0, stream>>>(
      x, nullptr, lin_a_w, lin_a_b, h, nullptr, N_NODES, IN_F, C_F, C_F, C_F);

  for (int l = 0; l < L_LAYERS; l++) {
    pack_kernel<<<dim3(320), blk, 0, stream>>>(bil_w, gate_w, wn, bil2, gw, Wz, l);
    // Wz[:,128:384] = wn[l] @ bil2   (128x128x256, tiny)
    gemm_kernel<false, false, 0, false, false, 0><<<dim3(2, 1), blk, 0, stream>>>(
        wn + (size_t)l * 16384, nullptr, bil2, nullptr, Wz + 128, nullptr, 128, C_F, 256, 256, 384);
    // [xn | z] = h @ Wz   (split-output; xn [N,128], z [N,256])
    gemm_kernel<false, false, 0, false, false, 1><<<dim3(3, (N_NODES + BM - 1) / BM), blk, 0, stream>>>(
        h, nullptr, Wz, nullptr, xn, z, N_NODES, C_F, 384, 384, 0);
    // pi/pj per node
    p_kernel<<<dim3((N_NODES * 64 + 255) / 256), blk, 0, stream>>>(
        xn, lin_w + (size_t)l * 768, p, N_NODES);

    zero_kernel<<<dim3((total_h + 255) / 256), blk, 0, stream>>>(hh, total_h);
    // fused: e = relu(attr@lbw.T+lbb), en = e@we[l], score, tanh, scatter
    edge_fused<<<dim3(N_EDGES / EPB), blk, 0, stream>>>(
        xn, z, edge_attr, p, lin_b_w, lin_b_b, we + (size_t)l * C_F * C_F,
        lin_w + (size_t)l * 768, lin_bias + (size_t)l * 2, ei, hh);

    // beta = sigmoid([h | relu(hh)] @ gw + gate_b[l])
    gemm_kernel<false, false, 2, true, true, 0><<<dim3(1, (N_NODES + BM - 1) / BM), blk, 0, stream>>>(
        h, hh, gw, gate_b + (size_t)l * C_F, beta, nullptr, N_NODES, 256, C_F, C_F, C_F);
    update_kernel<<<dim3((total_h + 255) / 256), blk, 0, stream>>>(h, hh, beta, total_h);

    // FeatureAttention
    zero_kernel<<<dim3((int)(2 * GH + 255) / 256), blk, 0, stream>>>(mx, (int)(2 * GH));
    seg_kernel<true><<<dim3((N_NODES + 15) / 16), blk, 0, stream>>>(h, batch, smv, mx, N_NODES);
    featmlp<<<dim3(G_GRAPHS), dim3(128), 0, stream>>>(
        mx, smv, att_w1 + (size_t)l * 32 * 128, att_w2 + (size_t)l * 128 * 32, yv);
    scale_kernel<<<dim3((total_h + 255) / 256), blk, 0, stream>>>(h, yv, batch, total_h);
  }

  // mol = relu(segment_sum(h)); out = mol @ out_w.T + out_b
  zero_kernel<<<dim3((int)(GH + 255) / 256), blk, 0, stream>>>(mol, (int)GH);
  seg_kernel<false><<<dim3((N_NODES + 15) / 16), blk, 0, stream>>>(h, batch, mol, nullptr, N_NODES);
  gemm_kernel<true, true, 0, true, false, 0><<<dim3(1, (G_GRAPHS + BM - 1) / BM), blk, 0, stream>>>(
      mol, nullptr, out_w, out_b, (float*)d_out, nullptr, G_GRAPHS, C_F, OUT_F, OUT_F, OUT_F);
}